// Round 1
// baseline (321.022 us; speedup 1.0000x reference)
//
#include <hip/hip_runtime.h>

#define DM 1024
#define NH 16
#define HD 64
#define SEQ 2048
#define BATCH 4
#define MROWS (BATCH*SEQ)   // 8192

typedef short short8 __attribute__((ext_vector_type(8)));
typedef float f32x4 __attribute__((ext_vector_type(4)));
typedef unsigned short u16x8 __attribute__((ext_vector_type(8)));
typedef unsigned short u16x4 __attribute__((ext_vector_type(4)));

__device__ inline unsigned short f2b(float f) {
    union { float f; unsigned u; } v; v.f = f;
    unsigned r = v.u + 0x7fffu + ((v.u >> 16) & 1u);   // RNE
    return (unsigned short)(r >> 16);
}

__device__ inline void gload_lds16(const void* g, void* l) {
    __builtin_amdgcn_global_load_lds(
        (const __attribute__((address_space(1))) void*)g,
        (__attribute__((address_space(3))) void*)l, 16, 0, 0);
}

// ---------------- convert x (fp32 -> bf16) ----------------
__global__ void k_cvt_x(const float* __restrict__ x, unsigned short* __restrict__ xb) {
    long i = ((long)blockIdx.x * 256 + threadIdx.x) * 8;
    float4 a = *reinterpret_cast<const float4*>(x + i);
    float4 b = *reinterpret_cast<const float4*>(x + i + 4);
    u16x8 o;
    o[0]=f2b(a.x); o[1]=f2b(a.y); o[2]=f2b(a.z); o[3]=f2b(a.w);
    o[4]=f2b(b.x); o[5]=f2b(b.y); o[6]=f2b(b.z); o[7]=f2b(b.w);
    *reinterpret_cast<u16x8*>(xb + i) = o;
}

// ---------------- convert + transpose W (fp32 [k][n] -> bf16 [n][k]) ----------------
__global__ void k_cvt_wT(const float* W0, const float* W1, const float* W2, const float* W3,
                         unsigned short* __restrict__ out) {
    const float* Ws[4] = {W0, W1, W2, W3};
    const float* W = Ws[blockIdx.z];
    unsigned short* o = out + (size_t)blockIdx.z * DM * DM;
    __shared__ float t[64][65];
    int tx = threadIdx.x & 15, ty = threadIdx.x >> 4;
    int nb = blockIdx.x * 64, kb = blockIdx.y * 64;
#pragma unroll
    for (int i = 0; i < 4; ++i) {
        int r = ty + 16 * i;
        float4 v = *reinterpret_cast<const float4*>(W + (size_t)(kb + r) * DM + nb + tx * 4);
        t[r][tx*4+0] = v.x; t[r][tx*4+1] = v.y; t[r][tx*4+2] = v.z; t[r][tx*4+3] = v.w;
    }
    __syncthreads();
#pragma unroll
    for (int i = 0; i < 4; ++i) {
        int r = ty + 16 * i;                  // n-local
        u16x4 pv;
#pragma unroll
        for (int j = 0; j < 4; ++j) pv[j] = f2b(t[tx*4+j][r]);
        *reinterpret_cast<u16x4*>(o + (size_t)(nb + r) * DM + kb + tx * 4) = pv;
    }
}

// ---------------- 128x128 bf16 MFMA GEMM ----------------
// A: [M][1024] bf16 row-major.  Bt: [N][1024] bf16 (B transposed).  K=1024.
// mode 0/1: out bf16 [B,H,S,Hd] (Q/K).  mode 2: out bf16 [B,H,Hd,S] (V^T).
// mode 3: out fp32 row-major [M][N] + bias.
#define BM 128
#define BN 128
#define BK 64

__global__ __launch_bounds__(256) void k_gemm(const unsigned short* __restrict__ A,
                                              const unsigned short* __restrict__ Bt,
                                              const float* __restrict__ bias,
                                              unsigned short* __restrict__ outb,
                                              float* __restrict__ outf, int mode) {
    __shared__ unsigned short lds[BM*BK + BN*BK];   // 32 KB
    unsigned short* lA = lds;
    unsigned short* lB = lds + BM*BK;
    int tid = threadIdx.x, lane = tid & 63, wv = tid >> 6;
    int wr = wv >> 1, wc = wv & 1;
    int c = lane & 15, g = lane >> 4;
    int m0 = blockIdx.x * BM, n0 = blockIdx.y * BN;
    f32x4 acc[4][4] = {};

    for (int kt = 0; kt < DM / BK; ++kt) {
#pragma unroll
        for (int it = 0; it < 4; ++it) {
            int sgi = it * 256 + tid;
            int row = sgi >> 3, blk = sgi & 7;
            int srcoff = kt * BK + ((blk ^ (row & 7)) << 3);
            gload_lds16(A  + (size_t)(m0 + row) * DM + srcoff, &lA[(it*256 + wv*64) * 8]);
            gload_lds16(Bt + (size_t)(n0 + row) * DM + srcoff, &lB[(it*256 + wv*64) * 8]);
        }
        __syncthreads();
#pragma unroll
        for (int ks = 0; ks < 2; ++ks) {
            short8 af[4], bf[4];
#pragma unroll
            for (int mi = 0; mi < 4; ++mi) {
                int row = wr*64 + mi*16 + c;
                af[mi] = *reinterpret_cast<const short8*>(&lA[row*64 + (((ks*4 + g) ^ (row & 7)) << 3)]);
            }
#pragma unroll
            for (int ni = 0; ni < 4; ++ni) {
                int row = wc*64 + ni*16 + c;
                bf[ni] = *reinterpret_cast<const short8*>(&lB[row*64 + (((ks*4 + g) ^ (row & 7)) << 3)]);
            }
#pragma unroll
            for (int mi = 0; mi < 4; ++mi)
#pragma unroll
                for (int ni = 0; ni < 4; ++ni)
                    acc[mi][ni] = __builtin_amdgcn_mfma_f32_16x16x32_bf16(af[mi], bf[ni], acc[mi][ni], 0, 0, 0);
        }
        __syncthreads();
    }

    if (mode <= 1) {                     // Q / K -> [B,H,S,Hd] bf16
#pragma unroll
        for (int mi = 0; mi < 4; ++mi)
#pragma unroll
            for (int ni = 0; ni < 4; ++ni)
#pragma unroll
                for (int r = 0; r < 4; ++r) {
                    int gr = m0 + wr*64 + mi*16 + 4*g + r;
                    int gc = n0 + wc*64 + ni*16 + c;
                    float v = acc[mi][ni][r] + bias[gc];
                    int b = gr >> 11, s = gr & 2047, h = gc >> 6, d = gc & 63;
                    outb[(((size_t)(b*NH + h) * SEQ + s) << 6) + d] = f2b(v);
                }
    } else if (mode == 2) {              // V^T -> [B,H,Hd,S] bf16 via LDS transpose
        unsigned short* t = lds;         // 128x128 ushorts = 32 KB exactly
#pragma unroll
        for (int mi = 0; mi < 4; ++mi)
#pragma unroll
            for (int ni = 0; ni < 4; ++ni)
#pragma unroll
                for (int r = 0; r < 4; ++r) {
                    int lr = wr*64 + mi*16 + 4*g + r;   // s-local
                    int lc = wc*64 + ni*16 + c;         // col-local
                    t[lc*128 + lr] = f2b(acc[mi][ni][r] + bias[n0 + lc]);
                }
        __syncthreads();
#pragma unroll
        for (int i = 0; i < 8; ++i) {
            int idx = (i*256 + tid) * 8;          // ushort offset in t
            int lc = idx >> 7, lr = idx & 127;
            int gcol = n0 + lc, grow = m0 + lr;
            int b = grow >> 11, s = grow & 2047, h = gcol >> 6, d = gcol & 63;
            *reinterpret_cast<u16x8*>(&outb[((size_t)((b*NH + h) << 6) + d) * SEQ + s]) =
                *reinterpret_cast<u16x8*>(&t[idx]);
        }
    } else {                             // final fp32 out + bias
#pragma unroll
        for (int mi = 0; mi < 4; ++mi)
#pragma unroll
            for (int ni = 0; ni < 4; ++ni)
#pragma unroll
                for (int r = 0; r < 4; ++r) {
                    int gr = m0 + wr*64 + mi*16 + 4*g + r;
                    int gc = n0 + wc*64 + ni*16 + c;
                    outf[(size_t)gr * DM + gc] = acc[mi][ni][r] + bias[gc];
                }
    }
}

// ---------------- flash attention ----------------
// grid (32 qblocks, 64 bh); 4 waves x 16 q-rows; KV tile 64.
__global__ __launch_bounds__(256) void k_attn(const unsigned short* __restrict__ Q,
                                              const unsigned short* __restrict__ K,
                                              const unsigned short* __restrict__ VT,
                                              unsigned short* __restrict__ AO) {
    __shared__ unsigned short kt[64*64], vt[64*64], pl[4][16*64];
    int tid = threadIdx.x, lane = tid & 63, wv = tid >> 6;
    int c = lane & 15, g = lane >> 4;
    int bh = blockIdx.y, qb = blockIdx.x;
    const unsigned short* Qh = Q  + (size_t)bh * SEQ * HD;
    const unsigned short* Kh = K  + (size_t)bh * SEQ * HD;
    const unsigned short* Vh = VT + (size_t)bh * HD * SEQ;

    int qrow = qb*64 + wv*16 + c;
    short8 qf[2];
    qf[0] = *reinterpret_cast<const short8*>(&Qh[(size_t)qrow*HD +      g*8]);
    qf[1] = *reinterpret_cast<const short8*>(&Qh[(size_t)qrow*HD + 32 + g*8]);

    float mr[4], lsum[4];
    f32x4 oacc[4] = {};
#pragma unroll
    for (int r = 0; r < 4; ++r) { mr[r] = -1e30f; lsum[r] = 0.f; }

    for (int t = 0; t < SEQ/64; ++t) {
#pragma unroll
        for (int it = 0; it < 2; ++it) {
            int sgi = it*256 + tid;
            int row = sgi >> 3, blk = sgi & 7;
            gload_lds16(Kh + (size_t)(t*64 + row)*HD + ((blk ^ (row & 7)) << 3),
                        &kt[(it*256 + wv*64) * 8]);
            gload_lds16(Vh + (size_t)row*SEQ + t*64 + ((blk ^ (row & 7)) << 3),
                        &vt[(it*256 + wv*64) * 8]);
        }
        __syncthreads();

        f32x4 sacc[4] = {};
#pragma unroll
        for (int ks = 0; ks < 2; ++ks)
#pragma unroll
            for (int nt = 0; nt < 4; ++nt) {
                int krow = nt*16 + c;
                short8 kf = *reinterpret_cast<const short8*>(
                    &kt[krow*64 + (((ks*4 + g) ^ (krow & 7)) << 3)]);
                sacc[nt] = __builtin_amdgcn_mfma_f32_16x16x32_bf16(qf[ks], kf, sacc[nt], 0, 0, 0);
            }
#pragma unroll
        for (int nt = 0; nt < 4; ++nt) sacc[nt] *= 0.125f;

        // online softmax (per lane: rows 4g+r, cols c of each 16-wide tile)
#pragma unroll
        for (int r = 0; r < 4; ++r) {
            float v = fmaxf(fmaxf(sacc[0][r], sacc[1][r]), fmaxf(sacc[2][r], sacc[3][r]));
#pragma unroll
            for (int o = 1; o < 16; o <<= 1) v = fmaxf(v, __shfl_xor(v, o, 64));
            float mn = fmaxf(mr[r], v);
            float corr = __expf(mr[r] - mn);
            mr[r] = mn;
            float s = 0.f;
#pragma unroll
            for (int nt = 0; nt < 4; ++nt) {
                float p = __expf(sacc[nt][r] - mn);
                sacc[nt][r] = p; s += p;
            }
#pragma unroll
            for (int o = 1; o < 16; o <<= 1) s += __shfl_xor(s, o, 64);
            lsum[r] = lsum[r]*corr + s;
#pragma unroll
            for (int ft = 0; ft < 4; ++ft) oacc[ft][r] *= corr;
        }

        // P -> LDS (bf16, swizzled)
        unsigned short* pw = pl[wv];
#pragma unroll
        for (int nt = 0; nt < 4; ++nt)
#pragma unroll
            for (int r = 0; r < 4; ++r) {
                int prow = 4*g + r, pcol = nt*16 + c;
                pw[prow*64 + (((pcol >> 3) ^ (prow & 7)) << 3) + (pcol & 7)] = f2b(sacc[nt][r]);
            }

        // PV
#pragma unroll
        for (int ks = 0; ks < 2; ++ks) {
            short8 pf = *reinterpret_cast<const short8*>(
                &pw[c*64 + (((ks*4 + g) ^ (c & 7)) << 3)]);
#pragma unroll
            for (int ft = 0; ft < 4; ++ft) {
                int vrow = ft*16 + c;
                short8 vf = *reinterpret_cast<const short8*>(
                    &vt[vrow*64 + (((ks*4 + g) ^ (vrow & 7)) << 3)]);
                oacc[ft] = __builtin_amdgcn_mfma_f32_16x16x32_bf16(pf, vf, oacc[ft], 0, 0, 0);
            }
        }
        __syncthreads();
    }

    int b = bh >> 4, h = bh & 15;
#pragma unroll
    for (int ft = 0; ft < 4; ++ft)
#pragma unroll
        for (int r = 0; r < 4; ++r) {
            int srow = qb*64 + wv*16 + 4*g + r;
            float val = oacc[ft][r] / lsum[r];
            AO[(size_t)(b*SEQ + srow) * DM + h*HD + ft*16 + c] = f2b(val);
        }
}

extern "C" void kernel_launch(void* const* d_in, const int* in_sizes, int n_in,
                              void* d_out, int out_size, void* d_ws, size_t ws_size,
                              hipStream_t stream) {
    const float* x  = (const float*)d_in[0];
    const float* Wq = (const float*)d_in[1];
    const float* bq = (const float*)d_in[2];
    const float* Wk = (const float*)d_in[3];
    const float* bk = (const float*)d_in[4];
    const float* Wv = (const float*)d_in[5];
    const float* bv = (const float*)d_in[6];
    const float* Wo = (const float*)d_in[7];
    const float* bo = (const float*)d_in[8];

    char* ws = (char*)d_ws;
    unsigned short* xb  = (unsigned short*)(ws);                  // 16 MB
    unsigned short* wT  = (unsigned short*)(ws + (16u<<20));      //  8 MB (4 mats)
    unsigned short* Qb  = (unsigned short*)(ws + (24u<<20));      // 16 MB
    unsigned short* Kb  = (unsigned short*)(ws + (40u<<20));      // 16 MB
    unsigned short* VTb = (unsigned short*)(ws + (56u<<20));      // 16 MB
    unsigned short* AOb = (unsigned short*)(ws + (72u<<20));      // 16 MB

    k_cvt_x<<<dim3(MROWS*DM/8/256), 256, 0, stream>>>(x, xb);
    k_cvt_wT<<<dim3(16,16,4), 256, 0, stream>>>(Wq, Wk, Wv, Wo, wT);

    k_gemm<<<dim3(MROWS/BM, DM/BN), 256, 0, stream>>>(xb, wT,            bq, Qb,  nullptr, 0);
    k_gemm<<<dim3(MROWS/BM, DM/BN), 256, 0, stream>>>(xb, wT + DM*DM,    bk, Kb,  nullptr, 1);
    k_gemm<<<dim3(MROWS/BM, DM/BN), 256, 0, stream>>>(xb, wT + 2*DM*DM,  bv, VTb, nullptr, 2);

    k_attn<<<dim3(SEQ/64, BATCH*NH), 256, 0, stream>>>(Qb, Kb, VTb, AOb);

    k_gemm<<<dim3(MROWS/BM, DM/BN), 256, 0, stream>>>(AOb, wT + 3*DM*DM, bo, nullptr, (float*)d_out, 3);
}

// Round 2
// 261.758 us; speedup vs baseline: 1.2264x; 1.2264x over previous
//
#include <hip/hip_runtime.h>

#define DM 1024
#define NH 16
#define HD 64
#define SEQ 2048
#define BATCH 4
#define MROWS (BATCH*SEQ)   // 8192

typedef short short8 __attribute__((ext_vector_type(8)));
typedef float f32x4 __attribute__((ext_vector_type(4)));
typedef unsigned short u16x8 __attribute__((ext_vector_type(8)));
typedef unsigned short u16x4 __attribute__((ext_vector_type(4)));

__device__ inline unsigned short f2b(float f) {
    union { float f; unsigned u; } v; v.f = f;
    unsigned r = v.u + 0x7fffu + ((v.u >> 16) & 1u);   // RNE
    return (unsigned short)(r >> 16);
}

__device__ inline void gload_lds16(const void* g, void* l) {
    __builtin_amdgcn_global_load_lds(
        (const __attribute__((address_space(1))) void*)g,
        (__attribute__((address_space(3))) void*)l, 16, 0, 0);
}

// ---------------- convert x (fp32 -> bf16) ----------------
__global__ void k_cvt_x(const float* __restrict__ x, unsigned short* __restrict__ xb) {
    long i = ((long)blockIdx.x * 256 + threadIdx.x) * 8;
    float4 a = *reinterpret_cast<const float4*>(x + i);
    float4 b = *reinterpret_cast<const float4*>(x + i + 4);
    u16x8 o;
    o[0]=f2b(a.x); o[1]=f2b(a.y); o[2]=f2b(a.z); o[3]=f2b(a.w);
    o[4]=f2b(b.x); o[5]=f2b(b.y); o[6]=f2b(b.z); o[7]=f2b(b.w);
    *reinterpret_cast<u16x8*>(xb + i) = o;
}

// ---------------- convert + transpose W (fp32 [k][n] -> bf16 [n][k]) ----------------
__global__ void k_cvt_wT(const float* W0, const float* W1, const float* W2, const float* W3,
                         unsigned short* __restrict__ out) {
    const float* Ws[4] = {W0, W1, W2, W3};
    const float* W = Ws[blockIdx.z];
    unsigned short* o = out + (size_t)blockIdx.z * DM * DM;
    __shared__ float t[64][65];
    int tx = threadIdx.x & 15, ty = threadIdx.x >> 4;
    int nb = blockIdx.x * 64, kb = blockIdx.y * 64;
#pragma unroll
    for (int i = 0; i < 4; ++i) {
        int r = ty + 16 * i;
        float4 v = *reinterpret_cast<const float4*>(W + (size_t)(kb + r) * DM + nb + tx * 4);
        t[r][tx*4+0] = v.x; t[r][tx*4+1] = v.y; t[r][tx*4+2] = v.z; t[r][tx*4+3] = v.w;
    }
    __syncthreads();
#pragma unroll
    for (int i = 0; i < 4; ++i) {
        int r = ty + 16 * i;                  // n-local
        u16x4 pv;
#pragma unroll
        for (int j = 0; j < 4; ++j) pv[j] = f2b(t[tx*4+j][r]);
        *reinterpret_cast<u16x4*>(o + (size_t)(nb + r) * DM + kb + tx * 4) = pv;
    }
}

// ---------------- 128x128 bf16 MFMA GEMM ----------------
#define BM 128
#define BN 128
#define BK 64
#define QSCALE 0.1803368801f   // 0.125 * log2(e)

__global__ __launch_bounds__(256) void k_gemm(const unsigned short* __restrict__ A,
                                              const unsigned short* __restrict__ Bt,
                                              const float* __restrict__ bias,
                                              unsigned short* __restrict__ outb,
                                              float* __restrict__ outf, int mode) {
    __shared__ unsigned short lds[BM*BK + BN*BK];   // 32 KB
    unsigned short* lA = lds;
    unsigned short* lB = lds + BM*BK;
    int tid = threadIdx.x, lane = tid & 63, wv = tid >> 6;
    int wr = wv >> 1, wc = wv & 1;
    int c = lane & 15, g = lane >> 4;
    int m0 = blockIdx.x * BM, n0 = blockIdx.y * BN;
    f32x4 acc[4][4] = {};

    for (int kt = 0; kt < DM / BK; ++kt) {
#pragma unroll
        for (int it = 0; it < 4; ++it) {
            int sgi = it * 256 + tid;
            int row = sgi >> 3, blk = sgi & 7;
            int srcoff = kt * BK + ((blk ^ (row & 7)) << 3);
            gload_lds16(A  + (size_t)(m0 + row) * DM + srcoff, &lA[(it*256 + wv*64) * 8]);
            gload_lds16(Bt + (size_t)(n0 + row) * DM + srcoff, &lB[(it*256 + wv*64) * 8]);
        }
        __syncthreads();
#pragma unroll
        for (int ks = 0; ks < 2; ++ks) {
            short8 af[4], bf[4];
#pragma unroll
            for (int mi = 0; mi < 4; ++mi) {
                int row = wr*64 + mi*16 + c;
                af[mi] = *reinterpret_cast<const short8*>(&lA[row*64 + (((ks*4 + g) ^ (row & 7)) << 3)]);
            }
#pragma unroll
            for (int ni = 0; ni < 4; ++ni) {
                int row = wc*64 + ni*16 + c;
                bf[ni] = *reinterpret_cast<const short8*>(&lB[row*64 + (((ks*4 + g) ^ (row & 7)) << 3)]);
            }
#pragma unroll
            for (int mi = 0; mi < 4; ++mi)
#pragma unroll
                for (int ni = 0; ni < 4; ++ni)
                    acc[mi][ni] = __builtin_amdgcn_mfma_f32_16x16x32_bf16(af[mi], bf[ni], acc[mi][ni], 0, 0, 0);
        }
        __syncthreads();
    }

    if (mode <= 1) {                     // Q / K -> [B,H,S,Hd] bf16  (Q pre-scaled)
        float sc = (mode == 0) ? QSCALE : 1.0f;
#pragma unroll
        for (int mi = 0; mi < 4; ++mi)
#pragma unroll
            for (int ni = 0; ni < 4; ++ni)
#pragma unroll
                for (int r = 0; r < 4; ++r) {
                    int gr = m0 + wr*64 + mi*16 + 4*g + r;
                    int gc = n0 + wc*64 + ni*16 + c;
                    float v = (acc[mi][ni][r] + bias[gc]) * sc;
                    int b = gr >> 11, s = gr & 2047, h = gc >> 6, d = gc & 63;
                    outb[(((size_t)(b*NH + h) * SEQ + s) << 6) + d] = f2b(v);
                }
    } else if (mode == 2) {              // V^T -> [B,H,Hd,S] bf16 via LDS transpose
        unsigned short* t = lds;         // 128x128 ushorts = 32 KB exactly
#pragma unroll
        for (int mi = 0; mi < 4; ++mi)
#pragma unroll
            for (int ni = 0; ni < 4; ++ni)
#pragma unroll
                for (int r = 0; r < 4; ++r) {
                    int lr = wr*64 + mi*16 + 4*g + r;   // s-local
                    int lc = wc*64 + ni*16 + c;         // col-local
                    t[lc*128 + lr] = f2b(acc[mi][ni][r] + bias[n0 + lc]);
                }
        __syncthreads();
#pragma unroll
        for (int i = 0; i < 8; ++i) {
            int idx = (i*256 + tid) * 8;          // ushort offset in t
            int lc = idx >> 7, lr = idx & 127;
            int gcol = n0 + lc, grow = m0 + lr;
            int b = grow >> 11, s = grow & 2047, h = gcol >> 6, d = gcol & 63;
            *reinterpret_cast<u16x8*>(&outb[((size_t)((b*NH + h) << 6) + d) * SEQ + s]) =
                *reinterpret_cast<u16x8*>(&t[idx]);
        }
    } else {                             // final fp32 out + bias
#pragma unroll
        for (int mi = 0; mi < 4; ++mi)
#pragma unroll
            for (int ni = 0; ni < 4; ++ni)
#pragma unroll
                for (int r = 0; r < 4; ++r) {
                    int gr = m0 + wr*64 + mi*16 + 4*g + r;
                    int gc = n0 + wc*64 + ni*16 + c;
                    outf[(size_t)gr * DM + gc] = acc[mi][ni][r] + bias[gc];
                }
    }
}

// ---------------- flash attention (swapped-QK, P in registers) ----------------
// grid 2048 blocks; XCD-swizzled so each XCD owns 8 heads end-to-end.
// 4 waves x 16 q-rows; KV tile 64, double-buffered.
__global__ __launch_bounds__(256) void k_attn(const unsigned short* __restrict__ Q,
                                              const unsigned short* __restrict__ K,
                                              const unsigned short* __restrict__ VT,
                                              unsigned short* __restrict__ AO) {
    __shared__ unsigned short kt[2][64*64], vt[2][64*64];   // 32 KB
    int tid = threadIdx.x, lane = tid & 63, wv = tid >> 6;
    int c = lane & 15, g = lane >> 4;

    // XCD swizzle: 2048 blocks, 8 XCDs -> XCD x gets heads [8x, 8x+8)
    int flat = blockIdx.x;
    int nb = (flat & 7) * 256 + (flat >> 3);
    int qb = nb & 31, bh = nb >> 5;

    const unsigned short* Qh = Q  + (size_t)bh * SEQ * HD;
    const unsigned short* Kh = K  + (size_t)bh * SEQ * HD;
    const unsigned short* Vh = VT + (size_t)bh * HD * SEQ;

    int qrow = qb*64 + wv*16 + c;
    short8 qf[2];
    qf[0] = *reinterpret_cast<const short8*>(&Qh[(size_t)qrow*HD +      g*8]);
    qf[1] = *reinterpret_cast<const short8*>(&Qh[(size_t)qrow*HD + 32 + g*8]);

    float m = -1e30f, l = 0.f;
    f32x4 oacc[4] = {};

    auto stage = [&](int buf, int t) {
#pragma unroll
        for (int it = 0; it < 2; ++it) {
            int sgi = it*256 + tid;
            int row = sgi >> 3, blk = sgi & 7;
            // sigma^-1: K rows permuted so QK output regs land in PV fragment order
            int srow = ((row >> 4) & 1)*32 + ((row >> 2) & 3)*8 + ((row >> 5) & 1)*4 + (row & 3);
            gload_lds16(Kh + (size_t)(t*64 + srow)*HD + ((blk ^ (row & 7)) << 3),
                        &kt[buf][(it*256 + wv*64) * 8]);
            gload_lds16(Vh + (size_t)row*SEQ + t*64 + ((blk ^ (row & 7)) << 3),
                        &vt[buf][(it*256 + wv*64) * 8]);
        }
    };

    stage(0, 0);
    __syncthreads();

    int cur = 0;
    for (int t = 0; t < SEQ/64; ++t) {
        if (t + 1 < SEQ/64) stage(cur ^ 1, t + 1);

        // QK^T swapped: lane (c,g) gets 16 scores for q-row c (log2-domain, pre-scaled)
        f32x4 sacc[4] = {};
#pragma unroll
        for (int ks = 0; ks < 2; ++ks)
#pragma unroll
            for (int nt = 0; nt < 4; ++nt) {
                int y = nt*16 + c;
                short8 kf = *reinterpret_cast<const short8*>(
                    &kt[cur][y*64 + (((ks*4 + g) ^ (y & 7)) << 3)]);
                sacc[nt] = __builtin_amdgcn_mfma_f32_16x16x32_bf16(kf, qf[ks], sacc[nt], 0, 0, 0);
            }

        // online softmax: 15 in-lane fmax + 2 shfls, exp2 domain
        float tm = sacc[0][0];
#pragma unroll
        for (int nt = 0; nt < 4; ++nt)
#pragma unroll
            for (int r = 0; r < 4; ++r) tm = fmaxf(tm, sacc[nt][r]);
        tm = fmaxf(tm, __shfl_xor(tm, 16, 64));
        tm = fmaxf(tm, __shfl_xor(tm, 32, 64));
        float mn = fmaxf(m, tm);
        float corr = exp2f(m - mn);
        m = mn;
        float s = 0.f;
#pragma unroll
        for (int nt = 0; nt < 4; ++nt)
#pragma unroll
            for (int r = 0; r < 4; ++r) {
                float p = exp2f(sacc[nt][r] - mn);
                sacc[nt][r] = p; s += p;
            }
        s += __shfl_xor(s, 16, 64);
        s += __shfl_xor(s, 32, 64);
        l = l * corr + s;
#pragma unroll
        for (int ft = 0; ft < 4; ++ft)
#pragma unroll
            for (int r = 0; r < 4; ++r) oacc[ft][r] *= corr;

        // P already in PV A-fragment order (via sigma): pack to bf16 in-register
        short8 pa[2];
#pragma unroll
        for (int j = 0; j < 4; ++j) {
            pa[0][j]   = (short)f2b(sacc[0][j]);
            pa[0][4+j] = (short)f2b(sacc[2][j]);
            pa[1][j]   = (short)f2b(sacc[1][j]);
            pa[1][4+j] = (short)f2b(sacc[3][j]);
        }

        // PV swapped: out^T = V^T . P^T
#pragma unroll
        for (int ks = 0; ks < 2; ++ks)
#pragma unroll
            for (int ft = 0; ft < 4; ++ft) {
                int y = ft*16 + c;
                short8 vf = *reinterpret_cast<const short8*>(
                    &vt[cur][y*64 + (((ks*4 + g) ^ (y & 7)) << 3)]);
                oacc[ft] = __builtin_amdgcn_mfma_f32_16x16x32_bf16(vf, pa[ks], oacc[ft], 0, 0, 0);
            }

        __syncthreads();
        cur ^= 1;
    }

    int b = bh >> 4, h = bh & 15;
    float inv = 1.f / l;
#pragma unroll
    for (int ft = 0; ft < 4; ++ft) {
        u16x4 o4;
#pragma unroll
        for (int r = 0; r < 4; ++r) o4[r] = f2b(oacc[ft][r] * inv);
        *reinterpret_cast<u16x4*>(
            &AO[(size_t)(b*SEQ + qrow) * DM + h*HD + ft*16 + 4*g]) = o4;
    }
}

extern "C" void kernel_launch(void* const* d_in, const int* in_sizes, int n_in,
                              void* d_out, int out_size, void* d_ws, size_t ws_size,
                              hipStream_t stream) {
    const float* x  = (const float*)d_in[0];
    const float* Wq = (const float*)d_in[1];
    const float* bq = (const float*)d_in[2];
    const float* Wk = (const float*)d_in[3];
    const float* bk = (const float*)d_in[4];
    const float* Wv = (const float*)d_in[5];
    const float* bv = (const float*)d_in[6];
    const float* Wo = (const float*)d_in[7];
    const float* bo = (const float*)d_in[8];

    char* ws = (char*)d_ws;
    unsigned short* xb  = (unsigned short*)(ws);                  // 16 MB
    unsigned short* wT  = (unsigned short*)(ws + (16u<<20));      //  8 MB (4 mats)
    unsigned short* Qb  = (unsigned short*)(ws + (24u<<20));      // 16 MB
    unsigned short* Kb  = (unsigned short*)(ws + (40u<<20));      // 16 MB
    unsigned short* VTb = (unsigned short*)(ws + (56u<<20));      // 16 MB
    unsigned short* AOb = (unsigned short*)(ws + (72u<<20));      // 16 MB

    k_cvt_x<<<dim3(MROWS*DM/8/256), 256, 0, stream>>>(x, xb);
    k_cvt_wT<<<dim3(16,16,4), 256, 0, stream>>>(Wq, Wk, Wv, Wo, wT);

    k_gemm<<<dim3(MROWS/BM, DM/BN), 256, 0, stream>>>(xb, wT,            bq, Qb,  nullptr, 0);
    k_gemm<<<dim3(MROWS/BM, DM/BN), 256, 0, stream>>>(xb, wT + DM*DM,    bk, Kb,  nullptr, 1);
    k_gemm<<<dim3(MROWS/BM, DM/BN), 256, 0, stream>>>(xb, wT + 2*DM*DM,  bv, VTb, nullptr, 2);

    k_attn<<<dim3(SEQ/64 * BATCH*NH), 256, 0, stream>>>(Qb, Kb, VTb, AOb);

    k_gemm<<<dim3(MROWS/BM, DM/BN), 256, 0, stream>>>(AOb, wT + 3*DM*DM, bo, nullptr, (float*)d_out, 3);
}

// Round 3
// 228.349 us; speedup vs baseline: 1.4058x; 1.1463x over previous
//
#include <hip/hip_runtime.h>

#define DM 1024
#define NH 16
#define HD 64
#define SEQ 2048
#define BATCH 4
#define MROWS (BATCH*SEQ)   // 8192

typedef short short8 __attribute__((ext_vector_type(8)));
typedef float f32x4 __attribute__((ext_vector_type(4)));
typedef unsigned short u16x8 __attribute__((ext_vector_type(8)));
typedef unsigned short u16x4 __attribute__((ext_vector_type(4)));

__device__ inline unsigned short f2b(float f) {
    union { float f; unsigned u; } v; v.f = f;
    unsigned r = v.u + 0x7fffu + ((v.u >> 16) & 1u);   // RNE
    return (unsigned short)(r >> 16);
}

__device__ inline void gload_lds16(const void* g, void* l) {
    __builtin_amdgcn_global_load_lds(
        (const __attribute__((address_space(1))) void*)g,
        (__attribute__((address_space(3))) void*)l, 16, 0, 0);
}

__device__ inline unsigned cvt_pk_bf16(float lo, float hi) {
    unsigned r;
    asm("v_cvt_pk_bf16_f32 %0, %1, %2" : "=v"(r) : "v"(lo), "v"(hi));
    return r;
}

// ---------------- convert x (fp32 -> bf16) ----------------
__global__ void k_cvt_x(const float* __restrict__ x, unsigned short* __restrict__ xb) {
    long i = ((long)blockIdx.x * 256 + threadIdx.x) * 8;
    float4 a = *reinterpret_cast<const float4*>(x + i);
    float4 b = *reinterpret_cast<const float4*>(x + i + 4);
    u16x8 o;
    o[0]=f2b(a.x); o[1]=f2b(a.y); o[2]=f2b(a.z); o[3]=f2b(a.w);
    o[4]=f2b(b.x); o[5]=f2b(b.y); o[6]=f2b(b.z); o[7]=f2b(b.w);
    *reinterpret_cast<u16x8*>(xb + i) = o;
}

// ---------------- convert + transpose W (fp32 [k][n] -> bf16 [n][k]) ----------------
__global__ void k_cvt_wT(const float* W0, const float* W1, const float* W2, const float* W3,
                         unsigned short* __restrict__ out) {
    const float* Ws[4] = {W0, W1, W2, W3};
    const float* W = Ws[blockIdx.z];
    unsigned short* o = out + (size_t)blockIdx.z * DM * DM;
    __shared__ float t[64][65];
    int tx = threadIdx.x & 15, ty = threadIdx.x >> 4;
    int nb = blockIdx.x * 64, kb = blockIdx.y * 64;
#pragma unroll
    for (int i = 0; i < 4; ++i) {
        int r = ty + 16 * i;
        float4 v = *reinterpret_cast<const float4*>(W + (size_t)(kb + r) * DM + nb + tx * 4);
        t[r][tx*4+0] = v.x; t[r][tx*4+1] = v.y; t[r][tx*4+2] = v.z; t[r][tx*4+3] = v.w;
    }
    __syncthreads();
#pragma unroll
    for (int i = 0; i < 4; ++i) {
        int r = ty + 16 * i;                  // n-local
        u16x4 pv;
#pragma unroll
        for (int j = 0; j < 4; ++j) pv[j] = f2b(t[tx*4+j][r]);
        *reinterpret_cast<u16x4*>(o + (size_t)(nb + r) * DM + kb + tx * 4) = pv;
    }
}

// ---------------- 128x128 bf16 MFMA GEMM ----------------
#define BM 128
#define BN 128
#define BK 64
#define QSCALE 0.1803368801f   // 0.125 * log2(e)

__global__ __launch_bounds__(256) void k_gemm(const unsigned short* __restrict__ A,
                                              const unsigned short* __restrict__ Bt,
                                              const float* __restrict__ bias,
                                              unsigned short* __restrict__ outb,
                                              float* __restrict__ outf, int mode) {
    __shared__ unsigned short lds[BM*BK + BN*BK];   // 32 KB
    unsigned short* lA = lds;
    unsigned short* lB = lds + BM*BK;
    int tid = threadIdx.x, lane = tid & 63, wv = tid >> 6;
    int wr = wv >> 1, wc = wv & 1;
    int c = lane & 15, g = lane >> 4;
    int m0 = blockIdx.x * BM, n0 = blockIdx.y * BN;
    f32x4 acc[4][4] = {};

    for (int kt = 0; kt < DM / BK; ++kt) {
#pragma unroll
        for (int it = 0; it < 4; ++it) {
            int sgi = it * 256 + tid;
            int row = sgi >> 3, blk = sgi & 7;
            int srcoff = kt * BK + ((blk ^ (row & 7)) << 3);
            gload_lds16(A  + (size_t)(m0 + row) * DM + srcoff, &lA[(it*256 + wv*64) * 8]);
            gload_lds16(Bt + (size_t)(n0 + row) * DM + srcoff, &lB[(it*256 + wv*64) * 8]);
        }
        __syncthreads();
#pragma unroll
        for (int ks = 0; ks < 2; ++ks) {
            short8 af[4], bf[4];
#pragma unroll
            for (int mi = 0; mi < 4; ++mi) {
                int row = wr*64 + mi*16 + c;
                af[mi] = *reinterpret_cast<const short8*>(&lA[row*64 + (((ks*4 + g) ^ (row & 7)) << 3)]);
            }
#pragma unroll
            for (int ni = 0; ni < 4; ++ni) {
                int row = wc*64 + ni*16 + c;
                bf[ni] = *reinterpret_cast<const short8*>(&lB[row*64 + (((ks*4 + g) ^ (row & 7)) << 3)]);
            }
#pragma unroll
            for (int mi = 0; mi < 4; ++mi)
#pragma unroll
                for (int ni = 0; ni < 4; ++ni)
                    acc[mi][ni] = __builtin_amdgcn_mfma_f32_16x16x32_bf16(af[mi], bf[ni], acc[mi][ni], 0, 0, 0);
        }
        __syncthreads();
    }

    if (mode <= 1) {                     // Q / K -> [B,H,S,Hd] bf16  (Q pre-scaled)
        float sc = (mode == 0) ? QSCALE : 1.0f;
#pragma unroll
        for (int mi = 0; mi < 4; ++mi)
#pragma unroll
            for (int ni = 0; ni < 4; ++ni)
#pragma unroll
                for (int r = 0; r < 4; ++r) {
                    int gr = m0 + wr*64 + mi*16 + 4*g + r;
                    int gc = n0 + wc*64 + ni*16 + c;
                    float v = (acc[mi][ni][r] + bias[gc]) * sc;
                    int b = gr >> 11, s = gr & 2047, h = gc >> 6, d = gc & 63;
                    outb[(((size_t)(b*NH + h) * SEQ + s) << 6) + d] = f2b(v);
                }
    } else if (mode == 2) {              // V^T -> [B,H,Hd,S] bf16 via LDS transpose
        unsigned short* t = lds;         // 128x128 ushorts = 32 KB exactly
#pragma unroll
        for (int mi = 0; mi < 4; ++mi)
#pragma unroll
            for (int ni = 0; ni < 4; ++ni)
#pragma unroll
                for (int r = 0; r < 4; ++r) {
                    int lr = wr*64 + mi*16 + 4*g + r;   // s-local
                    int lc = wc*64 + ni*16 + c;         // col-local
                    t[lc*128 + lr] = f2b(acc[mi][ni][r] + bias[n0 + lc]);
                }
        __syncthreads();
#pragma unroll
        for (int i = 0; i < 8; ++i) {
            int idx = (i*256 + tid) * 8;          // ushort offset in t
            int lc = idx >> 7, lr = idx & 127;
            int gcol = n0 + lc, grow = m0 + lr;
            int b = grow >> 11, s = grow & 2047, h = gcol >> 6, d = gcol & 63;
            *reinterpret_cast<u16x8*>(&outb[((size_t)((b*NH + h) << 6) + d) * SEQ + s]) =
                *reinterpret_cast<u16x8*>(&t[idx]);
        }
    } else {                             // final fp32 out + bias
#pragma unroll
        for (int mi = 0; mi < 4; ++mi)
#pragma unroll
            for (int ni = 0; ni < 4; ++ni)
#pragma unroll
                for (int r = 0; r < 4; ++r) {
                    int gr = m0 + wr*64 + mi*16 + 4*g + r;
                    int gc = n0 + wc*64 + ni*16 + c;
                    outf[(size_t)gr * DM + gc] = acc[mi][ni][r] + bias[gc];
                }
    }
}

// ---------------- flash attention (swapped-QK, P in registers) ----------------
// grid 2048 blocks; XCD-swizzled so each XCD owns 8 heads end-to-end.
// 4 waves x 16 q-rows; KV tile 64, double-buffered.
__global__ __launch_bounds__(256) void k_attn(const unsigned short* __restrict__ Q,
                                              const unsigned short* __restrict__ K,
                                              const unsigned short* __restrict__ VT,
                                              unsigned short* __restrict__ AO) {
    __shared__ unsigned short kt[2][64*64], vt[2][64*64];   // 32 KB
    int tid = threadIdx.x, lane = tid & 63, wv = tid >> 6;
    int c = lane & 15, g = lane >> 4;

    // XCD swizzle: 2048 blocks, 8 XCDs -> XCD x gets heads [8x, 8x+8)
    int flat = blockIdx.x;
    int nb = (flat & 7) * 256 + (flat >> 3);
    int qb = nb & 31, bh = nb >> 5;

    const unsigned short* Qh = Q  + (size_t)bh * SEQ * HD;
    const unsigned short* Kh = K  + (size_t)bh * SEQ * HD;
    const unsigned short* Vh = VT + (size_t)bh * HD * SEQ;

    int qrow = qb*64 + wv*16 + c;
    short8 qf[2];
    qf[0] = *reinterpret_cast<const short8*>(&Qh[(size_t)qrow*HD +      g*8]);
    qf[1] = *reinterpret_cast<const short8*>(&Qh[(size_t)qrow*HD + 32 + g*8]);

    float m = -1e30f, l = 0.f;
    f32x4 oacc[4] = {};

    auto stage = [&](int buf, int t) {
#pragma unroll
        for (int it = 0; it < 2; ++it) {
            int sgi = it*256 + tid;
            int row = sgi >> 3, blk = sgi & 7;
            // sigma^-1: K rows permuted so QK output regs land in PV fragment order
            int srow = ((row >> 4) & 1)*32 + ((row >> 2) & 3)*8 + ((row >> 5) & 1)*4 + (row & 3);
            gload_lds16(Kh + (size_t)(t*64 + srow)*HD + ((blk ^ (row & 7)) << 3),
                        &kt[buf][(it*256 + wv*64) * 8]);
            gload_lds16(Vh + (size_t)row*SEQ + t*64 + ((blk ^ (row & 7)) << 3),
                        &vt[buf][(it*256 + wv*64) * 8]);
        }
    };

    stage(0, 0);
    __syncthreads();

    int cur = 0;
    for (int t = 0; t < SEQ/64; ++t) {
        if (t + 1 < SEQ/64) stage(cur ^ 1, t + 1);

        // QK^T swapped: lane (c,g) gets 16 scores for q-row c (log2-domain, pre-scaled)
        f32x4 sacc[4] = {};
        __builtin_amdgcn_s_setprio(1);
#pragma unroll
        for (int ks = 0; ks < 2; ++ks)
#pragma unroll
            for (int nt = 0; nt < 4; ++nt) {
                int y = nt*16 + c;
                short8 kf = *reinterpret_cast<const short8*>(
                    &kt[cur][y*64 + (((ks*4 + g) ^ (y & 7)) << 3)]);
                sacc[nt] = __builtin_amdgcn_mfma_f32_16x16x32_bf16(kf, qf[ks], sacc[nt], 0, 0, 0);
            }
        __builtin_amdgcn_s_setprio(0);

        // tile row-max: 15 in-lane fmax (clang fuses to v_max3) + 2 shfls
        float t0 = fmaxf(fmaxf(sacc[0][0], sacc[0][1]), fmaxf(sacc[0][2], sacc[0][3]));
        float t1 = fmaxf(fmaxf(sacc[1][0], sacc[1][1]), fmaxf(sacc[1][2], sacc[1][3]));
        float t2 = fmaxf(fmaxf(sacc[2][0], sacc[2][1]), fmaxf(sacc[2][2], sacc[2][3]));
        float t3 = fmaxf(fmaxf(sacc[3][0], sacc[3][1]), fmaxf(sacc[3][2], sacc[3][3]));
        float tm = fmaxf(fmaxf(t0, t1), fmaxf(t2, t3));
        tm = fmaxf(tm, __shfl_xor(tm, 16, 64));
        tm = fmaxf(tm, __shfl_xor(tm, 32, 64));

        // defer-max (T13): only rescale when max grew by > 8 (log2 domain)
        if (!__all(tm <= m + 8.0f)) {
            float mn = fmaxf(m, tm);
            float corr = __builtin_amdgcn_exp2f(m - mn);
            m = mn;
            l *= corr;
#pragma unroll
            for (int ft = 0; ft < 4; ++ft)
#pragma unroll
                for (int r = 0; r < 4; ++r) oacc[ft][r] *= corr;
        }

        // P = exp2(S - m), balanced partial sums
        float s0 = 0.f, s1 = 0.f, s2 = 0.f, s3 = 0.f;
#pragma unroll
        for (int r = 0; r < 4; ++r) {
            float p0 = __builtin_amdgcn_exp2f(sacc[0][r] - m);
            float p1 = __builtin_amdgcn_exp2f(sacc[1][r] - m);
            float p2 = __builtin_amdgcn_exp2f(sacc[2][r] - m);
            float p3 = __builtin_amdgcn_exp2f(sacc[3][r] - m);
            sacc[0][r] = p0; sacc[1][r] = p1; sacc[2][r] = p2; sacc[3][r] = p3;
            s0 += p0; s1 += p1; s2 += p2; s3 += p3;
        }
        float s = (s0 + s1) + (s2 + s3);
        s += __shfl_xor(s, 16, 64);
        s += __shfl_xor(s, 32, 64);
        l += s;

        // pack P -> bf16 PV A-fragments via v_cvt_pk_bf16_f32 (8 instr, was 64)
        union { unsigned u[4]; short8 v; } U0, U1;
        U0.u[0] = cvt_pk_bf16(sacc[0][0], sacc[0][1]);
        U0.u[1] = cvt_pk_bf16(sacc[0][2], sacc[0][3]);
        U0.u[2] = cvt_pk_bf16(sacc[2][0], sacc[2][1]);
        U0.u[3] = cvt_pk_bf16(sacc[2][2], sacc[2][3]);
        U1.u[0] = cvt_pk_bf16(sacc[1][0], sacc[1][1]);
        U1.u[1] = cvt_pk_bf16(sacc[1][2], sacc[1][3]);
        U1.u[2] = cvt_pk_bf16(sacc[3][0], sacc[3][1]);
        U1.u[3] = cvt_pk_bf16(sacc[3][2], sacc[3][3]);
        short8 pa0 = U0.v, pa1 = U1.v;

        // PV swapped: out^T = V^T . P^T
        __builtin_amdgcn_s_setprio(1);
#pragma unroll
        for (int ft = 0; ft < 4; ++ft) {
            int y = ft*16 + c;
            short8 vf0 = *reinterpret_cast<const short8*>(
                &vt[cur][y*64 + ((g ^ (y & 7)) << 3)]);
            short8 vf1 = *reinterpret_cast<const short8*>(
                &vt[cur][y*64 + (((4 + g) ^ (y & 7)) << 3)]);
            oacc[ft] = __builtin_amdgcn_mfma_f32_16x16x32_bf16(vf0, pa0, oacc[ft], 0, 0, 0);
            oacc[ft] = __builtin_amdgcn_mfma_f32_16x16x32_bf16(vf1, pa1, oacc[ft], 0, 0, 0);
        }
        __builtin_amdgcn_s_setprio(0);

        __syncthreads();
        cur ^= 1;
    }

    int b = bh >> 4, h = bh & 15;
    float inv = 1.f / l;
#pragma unroll
    for (int ft = 0; ft < 4; ++ft) {
        u16x4 o4;
#pragma unroll
        for (int r = 0; r < 4; ++r) o4[r] = f2b(oacc[ft][r] * inv);
        *reinterpret_cast<u16x4*>(
            &AO[(size_t)(b*SEQ + qrow) * DM + h*HD + ft*16 + 4*g]) = o4;
    }
}

extern "C" void kernel_launch(void* const* d_in, const int* in_sizes, int n_in,
                              void* d_out, int out_size, void* d_ws, size_t ws_size,
                              hipStream_t stream) {
    const float* x  = (const float*)d_in[0];
    const float* Wq = (const float*)d_in[1];
    const float* bq = (const float*)d_in[2];
    const float* Wk = (const float*)d_in[3];
    const float* bk = (const float*)d_in[4];
    const float* Wv = (const float*)d_in[5];
    const float* bv = (const float*)d_in[6];
    const float* Wo = (const float*)d_in[7];
    const float* bo = (const float*)d_in[8];

    char* ws = (char*)d_ws;
    unsigned short* xb  = (unsigned short*)(ws);                  // 16 MB
    unsigned short* wT  = (unsigned short*)(ws + (16u<<20));      //  8 MB (4 mats)
    unsigned short* Qb  = (unsigned short*)(ws + (24u<<20));      // 16 MB
    unsigned short* Kb  = (unsigned short*)(ws + (40u<<20));      // 16 MB
    unsigned short* VTb = (unsigned short*)(ws + (56u<<20));      // 16 MB
    unsigned short* AOb = (unsigned short*)(ws + (72u<<20));      // 16 MB

    k_cvt_x<<<dim3(MROWS*DM/8/256), 256, 0, stream>>>(x, xb);
    k_cvt_wT<<<dim3(16,16,4), 256, 0, stream>>>(Wq, Wk, Wv, Wo, wT);

    k_gemm<<<dim3(MROWS/BM, DM/BN), 256, 0, stream>>>(xb, wT,            bq, Qb,  nullptr, 0);
    k_gemm<<<dim3(MROWS/BM, DM/BN), 256, 0, stream>>>(xb, wT + DM*DM,    bk, Kb,  nullptr, 1);
    k_gemm<<<dim3(MROWS/BM, DM/BN), 256, 0, stream>>>(xb, wT + 2*DM*DM,  bv, VTb, nullptr, 2);

    k_attn<<<dim3(SEQ/64 * BATCH*NH), 256, 0, stream>>>(Qb, Kb, VTb, AOb);

    k_gemm<<<dim3(MROWS/BM, DM/BN), 256, 0, stream>>>(AOb, wT + 3*DM*DM, bo, nullptr, (float*)d_out, 3);
}